// Round 6
// baseline (532.649 us; speedup 1.0000x reference)
//
#include <hip/hip_runtime.h>
#include <hip/hip_bf16.h>

#define L_SEQ 3120
#define LPAD  3200
#define DIMN  1536
#define FRAME 1560
#define NHH   12
#define HDIM  128

using bh8   = __attribute__((ext_vector_type(8))) short;
using bh4   = __attribute__((ext_vector_type(4))) short;
using f32x4 = __attribute__((ext_vector_type(4))) float;
typedef unsigned short u16;
typedef unsigned int   u32;

static __device__ __forceinline__ u16 f2bf(float f) {
  __hip_bfloat16 h = __float2bfloat16(f);
  return *reinterpret_cast<u16*>(&h);
}
static __device__ __forceinline__ void gld16(const u16* g, u16* l) {
  __builtin_amdgcn_global_load_lds((const __attribute__((address_space(1))) void*)g,
                                   (__attribute__((address_space(3))) void*)l, 16, 0, 0);
}

// ---------------- prep: x -> bf16, rows >= L zeroed ----------------
__global__ __launch_bounds__(256) void prep_x_kern(const float* __restrict__ x,
                                                   u16* __restrict__ xb) {
  int i = (blockIdx.x * 256 + threadIdx.x) * 8;   // grid covers LPAD*DIMN/8
  bh8 o;
  if (i < L_SEQ * DIMN) {
    float4 a = *(const float4*)&x[i];
    float4 b = *(const float4*)&x[i + 4];
    o[0] = (short)f2bf(a.x); o[1] = (short)f2bf(a.y);
    o[2] = (short)f2bf(a.z); o[3] = (short)f2bf(a.w);
    o[4] = (short)f2bf(b.x); o[5] = (short)f2bf(b.y);
    o[6] = (short)f2bf(b.z); o[7] = (short)f2bf(b.w);
  } else {
    o = (bh8){0, 0, 0, 0, 0, 0, 0, 0};
  }
  *(bh8*)&xb[i] = o;
}

// ---------------- weight transpose (fp32 -> bf16, W^T) ----------------
__global__ __launch_bounds__(256) void transpose_w_kern(const float* __restrict__ w0, const float* __restrict__ w1,
                                 const float* __restrict__ w2, const float* __restrict__ w3,
                                 u16* __restrict__ t0, u16* __restrict__ t1,
                                 u16* __restrict__ t2, u16* __restrict__ t3) {
  __shared__ float tile[32][33];
  const float* src; u16* dst;
  switch (blockIdx.z) {
    case 0:  src = w0; dst = t0; break;
    case 1:  src = w1; dst = t1; break;
    case 2:  src = w2; dst = t2; break;
    default: src = w3; dst = t3; break;
  }
  int k0 = blockIdx.x * 32, n0 = blockIdx.y * 32;
  int tx = threadIdx.x, ty = threadIdx.y;     // block (32,8)
  #pragma unroll
  for (int i = 0; i < 4; i++)
    tile[ty * 4 + i][tx] = src[(size_t)(k0 + ty * 4 + i) * DIMN + n0 + tx];
  __syncthreads();
  #pragma unroll
  for (int i = 0; i < 4; i++) {
    int ry = ty * 4 + i;
    dst[(size_t)(n0 + ry) * DIMN + k0 + tx] = f2bf(tile[tx][ry]);
  }
}

__global__ __launch_bounds__(256) void zero_tail_kern(u16* __restrict__ ob) {
  int i = (blockIdx.x * 256 + threadIdx.x) * 8;  // grid covers (LPAD-L_SEQ)*DIMN/8
  *(bh8*)&ob[L_SEQ * DIMN + i] = (bh8){0, 0, 0, 0, 0, 0, 0, 0};
}

// ---------------- fused QKV GEMM (m97 structure: global_load_lds, BK=64) ----------------
__global__ __launch_bounds__(256) void gemm_qkv(const u16* __restrict__ A,
                                                const u16* __restrict__ Bt,
                                                const float* __restrict__ bq,
                                                const float* __restrict__ bk,
                                                const float* __restrict__ bv,
                                                float* __restrict__ lin,
                                                u16* __restrict__ Vt) {
  __shared__ __align__(16) u16 Al[128 * 64];
  __shared__ __align__(16) u16 Bl[128 * 64];
  int t = threadIdx.x, lane = t & 63, w = t >> 6;
  int m0 = blockIdx.x * 128, n0 = blockIdx.y * 128;
  int wr = (w >> 1) * 64, wc = (w & 1) * 64;
  int r16 = lane & 15, g8 = (lane >> 4) * 8;
  int lrow = lane >> 3, lcol = (lane & 7) * 8;
  f32x4 acc[4][4];
  #pragma unroll
  for (int i = 0; i < 4; i++)
    #pragma unroll
    for (int j = 0; j < 4; j++) acc[i][j] = (f32x4){0.f, 0.f, 0.f, 0.f};

  const u16* Abase = A + (size_t)(m0 + w * 32 + lrow) * DIMN + lcol;
  const u16* Bbase = Bt + (size_t)(n0 + w * 32 + lrow) * DIMN + lcol;

  for (int kt = 0; kt < DIMN; kt += 64) {
    __syncthreads();
    #pragma unroll
    for (int j = 0; j < 4; j++) {
      gld16(Abase + (size_t)j * 8 * DIMN + kt, &Al[(w * 32 + j * 8) * 64]);
      gld16(Bbase + (size_t)j * 8 * DIMN + kt, &Bl[(w * 32 + j * 8) * 64]);
    }
    __syncthreads();
    bh8 af[2][4], bf[2][4];
    #pragma unroll
    for (int kk = 0; kk < 2; kk++) {
      #pragma unroll
      for (int i = 0; i < 4; i++)
        af[kk][i] = *(const bh8*)&Al[(wr + i * 16 + r16) * 64 + kk * 32 + g8];
      #pragma unroll
      for (int j = 0; j < 4; j++)
        bf[kk][j] = *(const bh8*)&Bl[(wc + j * 16 + r16) * 64 + kk * 32 + g8];
    }
    #pragma unroll
    for (int kk = 0; kk < 2; kk++)
      #pragma unroll
      for (int i = 0; i < 4; i++)
        #pragma unroll
        for (int j = 0; j < 4; j++)
          acc[i][j] = __builtin_amdgcn_mfma_f32_16x16x32_bf16(af[kk][i], bf[kk][j], acc[i][j], 0, 0, 0);
  }

  int cr = (lane >> 4) * 4, cc = lane & 15;
  int seg = n0 / DIMN;            // 0=q 1=k 2=v (tile never crosses a segment)
  int nb0 = n0 - seg * DIMN;
  const float* bp = (seg == 0) ? bq : (seg == 1) ? bk : bv;
  if (seg < 2) {
    #pragma unroll
    for (int j = 0; j < 4; j++) {
      int n = nb0 + wc + j * 16 + cc;
      float bvv = bp[n];
      #pragma unroll
      for (int i = 0; i < 4; i++) {
        int m = m0 + wr + i * 16 + cr;
        float* orow = lin + (size_t)m * (2 * DIMN) + seg * DIMN + n;
        #pragma unroll
        for (int r = 0; r < 4; r++) orow[(size_t)r * (2 * DIMN)] = acc[i][j][r] + bvv;
      }
    }
  } else {
    #pragma unroll
    for (int j = 0; j < 4; j++) {
      int d = nb0 + wc + j * 16 + cc;
      float bvv = bp[d];
      #pragma unroll
      for (int i = 0; i < 4; i++) {
        int m = m0 + wr + i * 16 + cr;
        if (m < L_SEQ) {
          bh4 o;
          #pragma unroll
          for (int r = 0; r < 4; r++) o[r] = (short)f2bf(acc[i][j][r] + bvv);
          *(bh4*)&Vt[(size_t)d * L_SEQ + m] = o;
        }
      }
    }
  }
}

// ---------------- out-proj GEMM ----------------
__global__ __launch_bounds__(256) void gemm_out(const u16* __restrict__ A,
                                                const u16* __restrict__ Bt,
                                                const float* __restrict__ bias,
                                                float* __restrict__ out) {
  __shared__ __align__(16) u16 Al[128 * 64];
  __shared__ __align__(16) u16 Bl[128 * 64];
  int t = threadIdx.x, lane = t & 63, w = t >> 6;
  int m0 = blockIdx.x * 128, n0 = blockIdx.y * 128;
  int wr = (w >> 1) * 64, wc = (w & 1) * 64;
  int r16 = lane & 15, g8 = (lane >> 4) * 8;
  int lrow = lane >> 3, lcol = (lane & 7) * 8;
  f32x4 acc[4][4];
  #pragma unroll
  for (int i = 0; i < 4; i++)
    #pragma unroll
    for (int j = 0; j < 4; j++) acc[i][j] = (f32x4){0.f, 0.f, 0.f, 0.f};

  const u16* Abase = A + (size_t)(m0 + w * 32 + lrow) * DIMN + lcol;
  const u16* Bbase = Bt + (size_t)(n0 + w * 32 + lrow) * DIMN + lcol;

  for (int kt = 0; kt < DIMN; kt += 64) {
    __syncthreads();
    #pragma unroll
    for (int j = 0; j < 4; j++) {
      gld16(Abase + (size_t)j * 8 * DIMN + kt, &Al[(w * 32 + j * 8) * 64]);
      gld16(Bbase + (size_t)j * 8 * DIMN + kt, &Bl[(w * 32 + j * 8) * 64]);
    }
    __syncthreads();
    bh8 af[2][4], bf[2][4];
    #pragma unroll
    for (int kk = 0; kk < 2; kk++) {
      #pragma unroll
      for (int i = 0; i < 4; i++)
        af[kk][i] = *(const bh8*)&Al[(wr + i * 16 + r16) * 64 + kk * 32 + g8];
      #pragma unroll
      for (int j = 0; j < 4; j++)
        bf[kk][j] = *(const bh8*)&Bl[(wc + j * 16 + r16) * 64 + kk * 32 + g8];
    }
    #pragma unroll
    for (int kk = 0; kk < 2; kk++)
      #pragma unroll
      for (int i = 0; i < 4; i++)
        #pragma unroll
        for (int j = 0; j < 4; j++)
          acc[i][j] = __builtin_amdgcn_mfma_f32_16x16x32_bf16(af[kk][i], bf[kk][j], acc[i][j], 0, 0, 0);
  }

  int cr = (lane >> 4) * 4, cc = lane & 15;
  #pragma unroll
  for (int j = 0; j < 4; j++) {
    int n = n0 + wc + j * 16 + cc;
    float bvv = bias[n];
    #pragma unroll
    for (int i = 0; i < 4; i++) {
      int m = m0 + wr + i * 16 + cr;
      if (m < L_SEQ) {
        #pragma unroll
        for (int r = 0; r < 4; r++) out[(size_t)(m + r) * DIMN + n] = acc[i][j][r] + bvv;
      }
    }
  }
}

// ---------------- fused RMSNorm + RoPE for q,k ----------------
__global__ __launch_bounds__(256) void postproc_qk(const float* __restrict__ lin,
                                                   const float* __restrict__ gq,
                                                   const float* __restrict__ gk,
                                                   const float* __restrict__ fc,
                                                   const float* __restrict__ fs,
                                                   u16* __restrict__ Qb, u16* __restrict__ Kb) {
  int l = blockIdx.x, t = threadIdx.x;
  int lane = t & 63, w = t >> 6;
  const float2* qr = (const float2*)(lin + (size_t)l * (2 * DIMN));
  const float2* kr = qr + DIMN / 2;
  float2 qv[3], kv[3];
  float ssq = 0.f, ssk = 0.f;
  #pragma unroll
  for (int j = 0; j < 3; j++) {
    qv[j] = qr[t + j * 256];
    kv[j] = kr[t + j * 256];
    ssq += qv[j].x * qv[j].x + qv[j].y * qv[j].y;
    ssk += kv[j].x * kv[j].x + kv[j].y * kv[j].y;
  }
  __shared__ float red[8];
  #pragma unroll
  for (int off = 32; off; off >>= 1) {
    ssq += __shfl_xor(ssq, off);
    ssk += __shfl_xor(ssk, off);
  }
  if (lane == 0) { red[w] = ssq; red[4 + w] = ssk; }
  __syncthreads();
  float rrq = rsqrtf((red[0] + red[1] + red[2] + red[3]) * (1.0f / DIMN) + 1e-6f);
  float rrk = rsqrtf((red[4] + red[5] + red[6] + red[7]) * (1.0f / DIMN) + 1e-6f);
  u32* qo = (u32*)Qb;
  u32* ko = (u32*)Kb;
  #pragma unroll
  for (int j = 0; j < 3; j++) {
    int p = t + j * 256;              // pair index 0..767
    int head = p >> 6, c = p & 63;
    float co = fc[l * 64 + c], si = fs[l * 64 + c];
    float2 g2, o;
    size_t idx = ((size_t)head * L_SEQ + l) * 64 + c;
    g2 = ((const float2*)gq)[p];
    o.x = qv[j].x * rrq * g2.x; o.y = qv[j].y * rrq * g2.y;
    qo[idx] = (u32)f2bf(o.x * co - o.y * si) | ((u32)f2bf(o.x * si + o.y * co) << 16);
    g2 = ((const float2*)gk)[p];
    o.x = kv[j].x * rrk * g2.x; o.y = kv[j].y * rrk * g2.y;
    ko[idx] = (u32)f2bf(o.x * co - o.y * si) | ((u32)f2bf(o.x * si + o.y * co) << 16);
  }
}

// ---------------- flash attention: QBLK=64, K in LDS (dbuf, XOR swizzle), V direct from L2 ----------------
// LDS 41 KB -> 3 blocks/CU; one barrier per tile; XCD head-chunk swizzle keeps K/V in L2.
__global__ __launch_bounds__(256, 3) void attn_kern(const u16* __restrict__ Q,
                                                    const u16* __restrict__ K,
                                                    const u16* __restrict__ Vt,
                                                    u16* __restrict__ Ob) {
  __shared__ __align__(16) u16 KlB[2][64 * 128];   // 32 KB
  __shared__ __align__(16) u16 Pl[4][16 * 72];     // 9 KB
  int t = threadIdx.x, lane = t & 63, w = t >> 6;
  // bijective XCD chunking: 588 blocks = 8 chunks (4x74 + 4x73), chunk = ~1.5 heads
  int id = blockIdx.x;
  int xcd = id & 7, sub = id >> 3;
  int g = (xcd < 4) ? (xcd * 74 + sub) : (296 + (xcd - 4) * 73 + sub);
  int h = g / 49, bx = g - h * 49;
  int qb = bx * 64, qr0 = qb + w * 16;
  int r16 = lane & 15, grp = lane >> 4, g8 = grp * 8;
  int cr = grp * 4, cc = lane & 15;
  const float sl = 0.08838834764831845f * 1.4426950408889634f;  // SCALE * log2(e)

  int qld = qr0 + r16; if (qld > L_SEQ - 1) qld = L_SEQ - 1;
  const u16* qrow = Q + ((size_t)h * L_SEQ + qld) * HDIM;
  bh8 qf[4];
  #pragma unroll
  for (int kk = 0; kk < 4; kk++) qf[kk] = *(const bh8*)&qrow[kk * 32 + g8];

  const u16* Kbase = K + (size_t)h * L_SEQ * HDIM;
  const u16* Vbase = Vt + (size_t)h * HDIM * L_SEQ;

  float m_run[4] = {-3.0e38f, -3.0e38f, -3.0e38f, -3.0e38f};
  float l_part[4] = {0.f, 0.f, 0.f, 0.f};
  f32x4 accO[8];
  #pragma unroll
  for (int i = 0; i < 8; i++) accO[i] = (f32x4){0.f, 0.f, 0.f, 0.f};

  int klim_min = (qr0 < FRAME) ? FRAME : L_SEQ;
  int klimr[4];
  #pragma unroll
  for (int r = 0; r < 4; r++) klimr[r] = (qr0 + cr + r < FRAME) ? FRAME : L_SEQ;
  int klimB = (qb + 63 < FRAME) ? FRAME : L_SEQ;
  int nkt = (klimB + 63) >> 6;

  // K staging only: 4 gld16/wave (16 rows of 128B), linear LDS dest, pre-swizzled source
  auto stageK = [&](int buf, int it) {
    int kt = it << 6;
    #pragma unroll
    for (int j = 0; j < 4; j++) {
      int rr = w * 16 + j * 4 + (lane >> 4);
      int grow = kt + rr; if (grow > L_SEQ - 1) grow = L_SEQ - 1;
      int gc = ((lane & 15) ^ (rr & 7)) * 8;
      gld16(Kbase + (size_t)grow * HDIM + gc, &KlB[buf][(w * 16 + j * 4) * 128]);
    }
  };

  stageK(0, 0);
  for (int it = 0; it < nkt; ++it) {
    int buf = it & 1, kt = it << 6;
    asm volatile("s_waitcnt vmcnt(0)" ::: "memory");   // own K-DMA retired (issued a full tile ago)
    __builtin_amdgcn_s_barrier();                      // all waves' K staged; prev-tile reads done
    __builtin_amdgcn_sched_barrier(0);

    // V fragments direct from global (L2-resident) — issue early, consumed after softmax
    bh8 vfr[16];
    #pragma unroll
    for (int nb = 0; nb < 8; nb++) {
      int vrow = nb * 16 + r16;
      const u16* vp = Vbase + (size_t)vrow * L_SEQ + kt;
      vfr[2 * nb]     = *(const bh8*)&vp[g8];
      vfr[2 * nb + 1] = *(const bh8*)&vp[32 + g8];
    }
    if (it + 1 < nkt) stageK(buf ^ 1, it + 1);         // K prefetch overlaps compute

    // QK^T (swizzled K reads)
    f32x4 s[4];
    #pragma unroll
    for (int sb = 0; sb < 4; sb++) s[sb] = (f32x4){0.f, 0.f, 0.f, 0.f};
    #pragma unroll
    for (int sb = 0; sb < 4; sb++) {
      int rr = sb * 16 + r16;
      bh8 kf[4];
      #pragma unroll
      for (int kk = 0; kk < 4; kk++)
        kf[kk] = *(const bh8*)&KlB[buf][rr * 128 + (((kk * 4 + grp) ^ (rr & 7)) * 8)];
      __builtin_amdgcn_s_setprio(1);
      #pragma unroll
      for (int kk = 0; kk < 4; kk++)
        s[sb] = __builtin_amdgcn_mfma_f32_16x16x32_bf16(qf[kk], kf[kk], s[sb], 0, 0, 0);
      __builtin_amdgcn_s_setprio(0);
    }

    // scale + boundary-only mask
    float v[4][4];
    if (kt + 64 > klim_min) {
      #pragma unroll
      for (int sb = 0; sb < 4; sb++) {
        int j = kt + sb * 16 + cc;
        #pragma unroll
        for (int r = 0; r < 4; r++) v[sb][r] = (j < klimr[r]) ? s[sb][r] * sl : -3.0e38f;
      }
    } else {
      #pragma unroll
      for (int sb = 0; sb < 4; sb++)
        #pragma unroll
        for (int r = 0; r < 4; r++) v[sb][r] = s[sb][r] * sl;
    }

    // defer-max online softmax (common path: no cross-lane ops)
    float loc[4];
    #pragma unroll
    for (int r = 0; r < 4; r++)
      loc[r] = fmaxf(fmaxf(v[0][r], v[1][r]), fmaxf(v[2][r], v[3][r]));
    bool need = (loc[0] > m_run[0] + 8.f) || (loc[1] > m_run[1] + 8.f) ||
                (loc[2] > m_run[2] + 8.f) || (loc[3] > m_run[3] + 8.f);
    if (__any((int)need)) {
      float facs[4];
      #pragma unroll
      for (int r = 0; r < 4; r++) {
        float mx = loc[r];
        mx = fmaxf(mx, __shfl_xor(mx, 1));
        mx = fmaxf(mx, __shfl_xor(mx, 2));
        mx = fmaxf(mx, __shfl_xor(mx, 4));
        mx = fmaxf(mx, __shfl_xor(mx, 8));
        float mnew = fmaxf(m_run[r], mx);
        facs[r] = exp2f(m_run[r] - mnew);
        m_run[r] = mnew;
        l_part[r] *= facs[r];
      }
      #pragma unroll
      for (int nb = 0; nb < 8; nb++)
        #pragma unroll
        for (int r = 0; r < 4; r++) accO[nb][r] *= facs[r];
    }
    #pragma unroll
    for (int sb = 0; sb < 4; sb++)
      #pragma unroll
      for (int r = 0; r < 4; r++) {
        float p = exp2f(v[sb][r] - m_run[r]);
        l_part[r] += p;
        Pl[w][(cr + r) * 72 + sb * 16 + cc] = f2bf(p);
      }

    bh8 pf0 = *(const bh8*)&Pl[w][r16 * 72 + g8];
    bh8 pf1 = *(const bh8*)&Pl[w][r16 * 72 + 32 + g8];
    __builtin_amdgcn_s_setprio(1);
    #pragma unroll
    for (int nb = 0; nb < 8; nb++) {
      accO[nb] = __builtin_amdgcn_mfma_f32_16x16x32_bf16(pf0, vfr[2 * nb],     accO[nb], 0, 0, 0);
      accO[nb] = __builtin_amdgcn_mfma_f32_16x16x32_bf16(pf1, vfr[2 * nb + 1], accO[nb], 0, 0, 0);
    }
    __builtin_amdgcn_s_setprio(0);
  }

  #pragma unroll
  for (int r = 0; r < 4; r++) {
    float lr = l_part[r];
    lr += __shfl_xor(lr, 1);
    lr += __shfl_xor(lr, 2);
    lr += __shfl_xor(lr, 4);
    lr += __shfl_xor(lr, 8);
    l_part[r] = 1.0f / lr;
  }
  #pragma unroll
  for (int nb = 0; nb < 8; nb++)
    #pragma unroll
    for (int r = 0; r < 4; r++) {
      int qi = qr0 + cr + r;
      if (qi < L_SEQ)
        Ob[(size_t)qi * DIMN + h * HDIM + nb * 16 + cc] = f2bf(accO[nb][r] * l_part[r]);
    }
}

// ---------------- host launch ----------------
extern "C" void kernel_launch(void* const* d_in, const int* in_sizes, int n_in,
                              void* d_out, int out_size, void* d_ws, size_t ws_size,
                              hipStream_t stream) {
  const float* x  = (const float*)d_in[0];
  const float* wq = (const float*)d_in[1];
  const float* wk = (const float*)d_in[2];
  const float* wv = (const float*)d_in[3];
  const float* wo = (const float*)d_in[4];
  const float* bq = (const float*)d_in[5];
  const float* bk = (const float*)d_in[6];
  const float* bv = (const float*)d_in[7];
  const float* bo = (const float*)d_in[8];
  const float* gq = (const float*)d_in[9];
  const float* gk = (const float*)d_in[10];
  const float* fc = (const float*)d_in[11];
  const float* fs = (const float*)d_in[12];

  char* ws = (char*)d_ws;
  u16* xb   = (u16*)(ws);                       // [3200][1536] bf16
  u16* Btq  = (u16*)(ws + 9830400);             // [4608][1536] bf16 (wq|wk|wv)^T
  u16* wot  = (u16*)(ws + 23986176);            // [1536][1536] bf16 wo^T
  u16* Qb   = (u16*)(ws + 28704768);            // [12][3120][128] bf16
  u16* Kb   = (u16*)(ws + 38289408);
  u16* Vt   = (u16*)(ws + 47874048);            // [1536][3120] bf16 (V^T)
  u16* Ob   = (u16*)(ws + 57458688);            // [3200][1536] bf16
  float* lin = (float*)(ws + 67289088);         // [3200][3072] fp32 (q|k)

  prep_x_kern<<<2400, 256, 0, stream>>>(x, xb);
  transpose_w_kern<<<dim3(48, 48, 4), dim3(32, 8), 0, stream>>>(
      wq, wk, wv, wo, Btq, Btq + DIMN * DIMN, Btq + 2 * DIMN * DIMN, wot);
  zero_tail_kern<<<60, 256, 0, stream>>>(Ob);

  gemm_qkv<<<dim3(25, 36), 256, 0, stream>>>(xb, Btq, bq, bk, bv, lin, Vt);
  postproc_qk<<<L_SEQ, 256, 0, stream>>>(lin, gq, gk, fc, fs, Qb, Kb);
  attn_kern<<<588, 256, 0, stream>>>(Qb, Kb, Vt, Ob);
  gemm_out<<<dim3(25, 12), 256, 0, stream>>>(Ob, wot, bo, (float*)d_out);
}

// Round 8
// 400.887 us; speedup vs baseline: 1.3287x; 1.3287x over previous
//
#include <hip/hip_runtime.h>
#include <hip/hip_bf16.h>

#define L_SEQ 3120
#define LPAD  3200
#define DIMN  1536
#define FRAME 1560
#define NHH   12
#define HDIM  128

using bh8   = __attribute__((ext_vector_type(8))) short;
using bh4   = __attribute__((ext_vector_type(4))) short;
using f32x4 = __attribute__((ext_vector_type(4))) float;
typedef unsigned short u16;
typedef unsigned int   u32;

static __device__ __forceinline__ u16 f2bf(float f) {
  __hip_bfloat16 h = __float2bfloat16(f);
  return *reinterpret_cast<u16*>(&h);
}
static __device__ __forceinline__ void gld16(const u16* g, u16* l) {
  __builtin_amdgcn_global_load_lds((const __attribute__((address_space(1))) void*)g,
                                   (__attribute__((address_space(3))) void*)l, 16, 0, 0);
}

// ---------------- prep: x -> bf16, rows >= L zeroed ----------------
__global__ __launch_bounds__(256) void prep_x_kern(const float* __restrict__ x,
                                                   u16* __restrict__ xb) {
  int i = (blockIdx.x * 256 + threadIdx.x) * 8;   // grid covers LPAD*DIMN/8
  bh8 o;
  if (i < L_SEQ * DIMN) {
    float4 a = *(const float4*)&x[i];
    float4 b = *(const float4*)&x[i + 4];
    o[0] = (short)f2bf(a.x); o[1] = (short)f2bf(a.y);
    o[2] = (short)f2bf(a.z); o[3] = (short)f2bf(a.w);
    o[4] = (short)f2bf(b.x); o[5] = (short)f2bf(b.y);
    o[6] = (short)f2bf(b.z); o[7] = (short)f2bf(b.w);
  } else {
    o = (bh8){0, 0, 0, 0, 0, 0, 0, 0};
  }
  *(bh8*)&xb[i] = o;
}

// ---------------- weight transpose (fp32 -> bf16, W^T) ----------------
__global__ __launch_bounds__(256) void transpose_w_kern(const float* __restrict__ w0, const float* __restrict__ w1,
                                 const float* __restrict__ w2, const float* __restrict__ w3,
                                 u16* __restrict__ t0, u16* __restrict__ t1,
                                 u16* __restrict__ t2, u16* __restrict__ t3) {
  __shared__ float tile[32][33];
  const float* src; u16* dst;
  switch (blockIdx.z) {
    case 0:  src = w0; dst = t0; break;
    case 1:  src = w1; dst = t1; break;
    case 2:  src = w2; dst = t2; break;
    default: src = w3; dst = t3; break;
  }
  int k0 = blockIdx.x * 32, n0 = blockIdx.y * 32;
  int tx = threadIdx.x, ty = threadIdx.y;     // block (32,8)
  #pragma unroll
  for (int i = 0; i < 4; i++)
    tile[ty * 4 + i][tx] = src[(size_t)(k0 + ty * 4 + i) * DIMN + n0 + tx];
  __syncthreads();
  #pragma unroll
  for (int i = 0; i < 4; i++) {
    int ry = ty * 4 + i;
    dst[(size_t)(n0 + ry) * DIMN + k0 + tx] = f2bf(tile[tx][ry]);
  }
}

__global__ __launch_bounds__(256) void zero_tail_kern(u16* __restrict__ ob) {
  int i = (blockIdx.x * 256 + threadIdx.x) * 8;  // grid covers (LPAD-L_SEQ)*DIMN/8
  *(bh8*)&ob[L_SEQ * DIMN + i] = (bh8){0, 0, 0, 0, 0, 0, 0, 0};
}

// ---------------- fused QKV GEMM (m97 structure: global_load_lds, BK=64) ----------------
__global__ __launch_bounds__(256) void gemm_qkv(const u16* __restrict__ A,
                                                const u16* __restrict__ Bt,
                                                const float* __restrict__ bq,
                                                const float* __restrict__ bk,
                                                const float* __restrict__ bv,
                                                float* __restrict__ lin,
                                                u16* __restrict__ Vt) {
  __shared__ __align__(16) u16 Al[128 * 64];
  __shared__ __align__(16) u16 Bl[128 * 64];
  int t = threadIdx.x, lane = t & 63, w = t >> 6;
  int m0 = blockIdx.x * 128, n0 = blockIdx.y * 128;
  int wr = (w >> 1) * 64, wc = (w & 1) * 64;
  int r16 = lane & 15, g8 = (lane >> 4) * 8;
  int lrow = lane >> 3, lcol = (lane & 7) * 8;
  f32x4 acc[4][4];
  #pragma unroll
  for (int i = 0; i < 4; i++)
    #pragma unroll
    for (int j = 0; j < 4; j++) acc[i][j] = (f32x4){0.f, 0.f, 0.f, 0.f};

  const u16* Abase = A + (size_t)(m0 + w * 32 + lrow) * DIMN + lcol;
  const u16* Bbase = Bt + (size_t)(n0 + w * 32 + lrow) * DIMN + lcol;

  for (int kt = 0; kt < DIMN; kt += 64) {
    __syncthreads();
    #pragma unroll
    for (int j = 0; j < 4; j++) {
      gld16(Abase + (size_t)j * 8 * DIMN + kt, &Al[(w * 32 + j * 8) * 64]);
      gld16(Bbase + (size_t)j * 8 * DIMN + kt, &Bl[(w * 32 + j * 8) * 64]);
    }
    __syncthreads();
    bh8 af[2][4], bf[2][4];
    #pragma unroll
    for (int kk = 0; kk < 2; kk++) {
      #pragma unroll
      for (int i = 0; i < 4; i++)
        af[kk][i] = *(const bh8*)&Al[(wr + i * 16 + r16) * 64 + kk * 32 + g8];
      #pragma unroll
      for (int j = 0; j < 4; j++)
        bf[kk][j] = *(const bh8*)&Bl[(wc + j * 16 + r16) * 64 + kk * 32 + g8];
    }
    #pragma unroll
    for (int kk = 0; kk < 2; kk++)
      #pragma unroll
      for (int i = 0; i < 4; i++)
        #pragma unroll
        for (int j = 0; j < 4; j++)
          acc[i][j] = __builtin_amdgcn_mfma_f32_16x16x32_bf16(af[kk][i], bf[kk][j], acc[i][j], 0, 0, 0);
  }

  int cr = (lane >> 4) * 4, cc = lane & 15;
  int seg = n0 / DIMN;            // 0=q 1=k 2=v (tile never crosses a segment)
  int nb0 = n0 - seg * DIMN;
  const float* bp = (seg == 0) ? bq : (seg == 1) ? bk : bv;
  if (seg < 2) {
    #pragma unroll
    for (int j = 0; j < 4; j++) {
      int n = nb0 + wc + j * 16 + cc;
      float bvv = bp[n];
      #pragma unroll
      for (int i = 0; i < 4; i++) {
        int m = m0 + wr + i * 16 + cr;
        float* orow = lin + (size_t)m * (2 * DIMN) + seg * DIMN + n;
        #pragma unroll
        for (int r = 0; r < 4; r++) orow[(size_t)r * (2 * DIMN)] = acc[i][j][r] + bvv;
      }
    }
  } else {
    #pragma unroll
    for (int j = 0; j < 4; j++) {
      int d = nb0 + wc + j * 16 + cc;
      float bvv = bp[d];
      #pragma unroll
      for (int i = 0; i < 4; i++) {
        int m = m0 + wr + i * 16 + cr;
        if (m < L_SEQ) {
          bh4 o;
          #pragma unroll
          for (int r = 0; r < 4; r++) o[r] = (short)f2bf(acc[i][j][r] + bvv);
          *(bh4*)&Vt[(size_t)d * L_SEQ + m] = o;
        }
      }
    }
  }
}

// ---------------- out-proj GEMM ----------------
__global__ __launch_bounds__(256) void gemm_out(const u16* __restrict__ A,
                                                const u16* __restrict__ Bt,
                                                const float* __restrict__ bias,
                                                float* __restrict__ out) {
  __shared__ __align__(16) u16 Al[128 * 64];
  __shared__ __align__(16) u16 Bl[128 * 64];
  int t = threadIdx.x, lane = t & 63, w = t >> 6;
  int m0 = blockIdx.x * 128, n0 = blockIdx.y * 128;
  int wr = (w >> 1) * 64, wc = (w & 1) * 64;
  int r16 = lane & 15, g8 = (lane >> 4) * 8;
  int lrow = lane >> 3, lcol = (lane & 7) * 8;
  f32x4 acc[4][4];
  #pragma unroll
  for (int i = 0; i < 4; i++)
    #pragma unroll
    for (int j = 0; j < 4; j++) acc[i][j] = (f32x4){0.f, 0.f, 0.f, 0.f};

  const u16* Abase = A + (size_t)(m0 + w * 32 + lrow) * DIMN + lcol;
  const u16* Bbase = Bt + (size_t)(n0 + w * 32 + lrow) * DIMN + lcol;

  for (int kt = 0; kt < DIMN; kt += 64) {
    __syncthreads();
    #pragma unroll
    for (int j = 0; j < 4; j++) {
      gld16(Abase + (size_t)j * 8 * DIMN + kt, &Al[(w * 32 + j * 8) * 64]);
      gld16(Bbase + (size_t)j * 8 * DIMN + kt, &Bl[(w * 32 + j * 8) * 64]);
    }
    __syncthreads();
    bh8 af[2][4], bf[2][4];
    #pragma unroll
    for (int kk = 0; kk < 2; kk++) {
      #pragma unroll
      for (int i = 0; i < 4; i++)
        af[kk][i] = *(const bh8*)&Al[(wr + i * 16 + r16) * 64 + kk * 32 + g8];
      #pragma unroll
      for (int j = 0; j < 4; j++)
        bf[kk][j] = *(const bh8*)&Bl[(wc + j * 16 + r16) * 64 + kk * 32 + g8];
    }
    #pragma unroll
    for (int kk = 0; kk < 2; kk++)
      #pragma unroll
      for (int i = 0; i < 4; i++)
        #pragma unroll
        for (int j = 0; j < 4; j++)
          acc[i][j] = __builtin_amdgcn_mfma_f32_16x16x32_bf16(af[kk][i], bf[kk][j], acc[i][j], 0, 0, 0);
  }

  int cr = (lane >> 4) * 4, cc = lane & 15;
  #pragma unroll
  for (int j = 0; j < 4; j++) {
    int n = n0 + wc + j * 16 + cc;
    float bvv = bias[n];
    #pragma unroll
    for (int i = 0; i < 4; i++) {
      int m = m0 + wr + i * 16 + cr;
      if (m < L_SEQ) {
        #pragma unroll
        for (int r = 0; r < 4; r++) out[(size_t)(m + r) * DIMN + n] = acc[i][j][r] + bvv;
      }
    }
  }
}

// ---------------- fused RMSNorm + RoPE for q,k ----------------
__global__ __launch_bounds__(256) void postproc_qk(const float* __restrict__ lin,
                                                   const float* __restrict__ gq,
                                                   const float* __restrict__ gk,
                                                   const float* __restrict__ fc,
                                                   const float* __restrict__ fs,
                                                   u16* __restrict__ Qb, u16* __restrict__ Kb) {
  int l = blockIdx.x, t = threadIdx.x;
  int lane = t & 63, w = t >> 6;
  const float2* qr = (const float2*)(lin + (size_t)l * (2 * DIMN));
  const float2* kr = qr + DIMN / 2;
  float2 qv[3], kv[3];
  float ssq = 0.f, ssk = 0.f;
  #pragma unroll
  for (int j = 0; j < 3; j++) {
    qv[j] = qr[t + j * 256];
    kv[j] = kr[t + j * 256];
    ssq += qv[j].x * qv[j].x + qv[j].y * qv[j].y;
    ssk += kv[j].x * kv[j].x + kv[j].y * kv[j].y;
  }
  __shared__ float red[8];
  #pragma unroll
  for (int off = 32; off; off >>= 1) {
    ssq += __shfl_xor(ssq, off);
    ssk += __shfl_xor(ssk, off);
  }
  if (lane == 0) { red[w] = ssq; red[4 + w] = ssk; }
  __syncthreads();
  float rrq = rsqrtf((red[0] + red[1] + red[2] + red[3]) * (1.0f / DIMN) + 1e-6f);
  float rrk = rsqrtf((red[4] + red[5] + red[6] + red[7]) * (1.0f / DIMN) + 1e-6f);
  u32* qo = (u32*)Qb;
  u32* ko = (u32*)Kb;
  #pragma unroll
  for (int j = 0; j < 3; j++) {
    int p = t + j * 256;              // pair index 0..767
    int head = p >> 6, c = p & 63;
    float co = fc[l * 64 + c], si = fs[l * 64 + c];
    float2 g2, o;
    size_t idx = ((size_t)head * L_SEQ + l) * 64 + c;
    g2 = ((const float2*)gq)[p];
    o.x = qv[j].x * rrq * g2.x; o.y = qv[j].y * rrq * g2.y;
    qo[idx] = (u32)f2bf(o.x * co - o.y * si) | ((u32)f2bf(o.x * si + o.y * co) << 16);
    g2 = ((const float2*)gk)[p];
    o.x = kv[j].x * rrk * g2.x; o.y = kv[j].y * rrk * g2.y;
    ko[idx] = (u32)f2bf(o.x * co - o.y * si) | ((u32)f2bf(o.x * si + o.y * co) << 16);
  }
}

// ---------------- flash attention (R4 structure + XCD chunk remap) ----------------
// QBLK=64, KVBLK=64, K+V DMA-staged, double-buffered, counted vmcnt(8).
// XCD remap: 588 blocks -> 8 chunks (4x74+4x73); chunk spans ~1.5 heads so K/V stay L2-resident.
__global__ __launch_bounds__(256) void attn_kern(const u16* __restrict__ Q,
                                                 const u16* __restrict__ K,
                                                 const u16* __restrict__ Vt,
                                                 u16* __restrict__ Ob) {
  __shared__ __align__(16) u16 KlB[2][64 * 128];   // 32 KB
  __shared__ __align__(16) u16 VlB[2][128 * 64];   // 32 KB
  __shared__ __align__(16) u16 Pl[4][16 * 72];     // 9 KB
  int t = threadIdx.x, lane = t & 63, w = t >> 6;
  int id = blockIdx.x;                             // 0..587
  int xcd = id & 7, sub = id >> 3;
  int g = (xcd < 4) ? (xcd * 74 + sub) : (296 + (xcd - 4) * 73 + sub);
  int h = g / 49;
  int bx = 48 - (g - h * 49);                      // heavy (full-causal) blocks first
  int qb = bx * 64, qr0 = qb + w * 16;
  int r16 = lane & 15, grp = lane >> 4, g8 = grp * 8;
  int cr = grp * 4, cc = lane & 15;
  const float sl = 0.08838834764831845f * 1.4426950408889634f;  // SCALE * log2(e)

  int qld = qr0 + r16; if (qld > L_SEQ - 1) qld = L_SEQ - 1;
  const u16* qrow = Q + ((size_t)h * L_SEQ + qld) * HDIM;
  bh8 qf[4];
  #pragma unroll
  for (int kk = 0; kk < 4; kk++) qf[kk] = *(const bh8*)&qrow[kk * 32 + g8];

  const u16* Kbase = K + (size_t)h * L_SEQ * HDIM;
  const u16* Vbase = Vt + (size_t)h * HDIM * L_SEQ;

  float m_run[4] = {-3.0e38f, -3.0e38f, -3.0e38f, -3.0e38f};
  float l_part[4] = {0.f, 0.f, 0.f, 0.f};
  f32x4 accO[8];
  #pragma unroll
  for (int i = 0; i < 8; i++) accO[i] = (f32x4){0.f, 0.f, 0.f, 0.f};

  int klim_min = (qr0 < FRAME) ? FRAME : L_SEQ;
  int klimr[4];
  #pragma unroll
  for (int r = 0; r < 4; r++) klimr[r] = (qr0 + cr + r < FRAME) ? FRAME : L_SEQ;
  int klimB = (qb + 63 < FRAME) ? FRAME : L_SEQ;
  int nkt = (klimB + 63) >> 6;

  // 8 gld16 per wave per tile (K: 16 rows of 4x16B; V: 32 rows of 8x16B)
  auto stage = [&](int buf, int it) {
    int kt = it << 6;
    #pragma unroll
    for (int j = 0; j < 4; j++) {
      int rr = w * 16 + j * 4 + (lane >> 4);
      int grow = kt + rr; grow = (grow > L_SEQ - 1) ? L_SEQ - 1 : grow;
      int gc = ((lane & 15) ^ (rr & 7)) * 8;
      gld16(Kbase + (size_t)grow * HDIM + gc, &KlB[buf][(w * 16 + j * 4) * 128]);
    }
    #pragma unroll
    for (int j = 0; j < 4; j++) {
      int vr = w * 32 + j * 8 + (lane >> 3);
      int gc = kt + ((lane & 7) ^ (vr & 7)) * 8;
      gc = (gc > L_SEQ - 8) ? L_SEQ - 8 : gc;
      gld16(Vbase + (size_t)vr * L_SEQ + gc, &VlB[buf][(w * 32 + j * 8) * 64]);
    }
  };

  stage(0, 0);
  for (int it = 0; it < nkt; ++it) {
    int buf = it & 1, kt = it << 6;
    if (it + 1 < nkt) {
      stage(buf ^ 1, it + 1);
      asm volatile("s_waitcnt vmcnt(8)" ::: "memory");   // tile-it loads retired
    } else {
      asm volatile("s_waitcnt vmcnt(0)" ::: "memory");
    }
    __builtin_amdgcn_s_barrier();
    __builtin_amdgcn_sched_barrier(0);

    // QK^T (swizzled K reads)
    f32x4 s[4];
    #pragma unroll
    for (int sb = 0; sb < 4; sb++) s[sb] = (f32x4){0.f, 0.f, 0.f, 0.f};
    #pragma unroll
    for (int kk = 0; kk < 4; kk++)
      #pragma unroll
      for (int sb = 0; sb < 4; sb++) {
        int rr = sb * 16 + r16;
        bh8 kf = *(const bh8*)&KlB[buf][rr * 128 + (((kk * 4 + grp) ^ (rr & 7)) * 8)];
        s[sb] = __builtin_amdgcn_mfma_f32_16x16x32_bf16(qf[kk], kf, s[sb], 0, 0, 0);
      }

    // scale + boundary-only mask
    float v[4][4];
    if (kt + 64 > klim_min) {
      #pragma unroll
      for (int sb = 0; sb < 4; sb++) {
        int j = kt + sb * 16 + cc;
        #pragma unroll
        for (int r = 0; r < 4; r++) v[sb][r] = (j < klimr[r]) ? s[sb][r] * sl : -3.0e38f;
      }
    } else {
      #pragma unroll
      for (int sb = 0; sb < 4; sb++)
        #pragma unroll
        for (int r = 0; r < 4; r++) v[sb][r] = s[sb][r] * sl;
    }

    // defer-max online softmax (common path: no cross-lane ops)
    float loc[4];
    #pragma unroll
    for (int r = 0; r < 4; r++)
      loc[r] = fmaxf(fmaxf(v[0][r], v[1][r]), fmaxf(v[2][r], v[3][r]));
    bool need = (loc[0] > m_run[0] + 8.f) || (loc[1] > m_run[1] + 8.f) ||
                (loc[2] > m_run[2] + 8.f) || (loc[3] > m_run[3] + 8.f);
    if (__any((int)need)) {
      float facs[4];
      #pragma unroll
      for (int r = 0; r < 4; r++) {
        float mx = loc[r];
        mx = fmaxf(mx, __shfl_xor(mx, 1));
        mx = fmaxf(mx, __shfl_xor(mx, 2));
        mx = fmaxf(mx, __shfl_xor(mx, 4));
        mx = fmaxf(mx, __shfl_xor(mx, 8));
        float mnew = fmaxf(m_run[r], mx);
        facs[r] = exp2f(m_run[r] - mnew);
        m_run[r] = mnew;
        l_part[r] *= facs[r];
      }
      #pragma unroll
      for (int nb = 0; nb < 8; nb++)
        #pragma unroll
        for (int r = 0; r < 4; r++) accO[nb][r] *= facs[r];
    }
    #pragma unroll
    for (int sb = 0; sb < 4; sb++)
      #pragma unroll
      for (int r = 0; r < 4; r++) {
        float p = exp2f(v[sb][r] - m_run[r]);
        l_part[r] += p;
        Pl[w][(cr + r) * 72 + sb * 16 + cc] = f2bf(p);
      }

    bh8 pf0 = *(const bh8*)&Pl[w][r16 * 72 + g8];
    bh8 pf1 = *(const bh8*)&Pl[w][r16 * 72 + 32 + g8];
    #pragma unroll
    for (int nb = 0; nb < 8; nb++) {
      int vrow = nb * 16 + r16;
      bh8 vf0 = *(const bh8*)&VlB[buf][vrow * 64 + ((grp ^ (vrow & 7)) * 8)];
      bh8 vf1 = *(const bh8*)&VlB[buf][vrow * 64 + (((4 + grp) ^ (vrow & 7)) * 8)];
      accO[nb] = __builtin_amdgcn_mfma_f32_16x16x32_bf16(pf0, vf0, accO[nb], 0, 0, 0);
      accO[nb] = __builtin_amdgcn_mfma_f32_16x16x32_bf16(pf1, vf1, accO[nb], 0, 0, 0);
    }
    __builtin_amdgcn_s_barrier();   // all waves done reading buf before it's re-staged
  }

  #pragma unroll
  for (int r = 0; r < 4; r++) {
    float lr = l_part[r];
    lr += __shfl_xor(lr, 1);
    lr += __shfl_xor(lr, 2);
    lr += __shfl_xor(lr, 4);
    lr += __shfl_xor(lr, 8);
    l_part[r] = 1.0f / lr;
  }
  #pragma unroll
  for (int nb = 0; nb < 8; nb++)
    #pragma unroll
    for (int r = 0; r < 4; r++) {
      int qi = qr0 + cr + r;
      if (qi < L_SEQ)
        Ob[(size_t)qi * DIMN + h * HDIM + nb * 16 + cc] = f2bf(accO[nb][r] * l_part[r]);
    }
}

// ---------------- host launch ----------------
extern "C" void kernel_launch(void* const* d_in, const int* in_sizes, int n_in,
                              void* d_out, int out_size, void* d_ws, size_t ws_size,
                              hipStream_t stream) {
  const float* x  = (const float*)d_in[0];
  const float* wq = (const float*)d_in[1];
  const float* wk = (const float*)d_in[2];
  const float* wv = (const float*)d_in[3];
  const float* wo = (const float*)d_in[4];
  const float* bq = (const float*)d_in[5];
  const float* bk = (const float*)d_in[6];
  const float* bv = (const float*)d_in[7];
  const float* bo = (const float*)d_in[8];
  const float* gq = (const float*)d_in[9];
  const float* gk = (const float*)d_in[10];
  const float* fc = (const float*)d_in[11];
  const float* fs = (const float*)d_in[12];

  char* ws = (char*)d_ws;
  u16* xb   = (u16*)(ws);                       // [3200][1536] bf16
  u16* Btq  = (u16*)(ws + 9830400);             // [4608][1536] bf16 (wq|wk|wv)^T
  u16* wot  = (u16*)(ws + 23986176);            // [1536][1536] bf16 wo^T
  u16* Qb   = (u16*)(ws + 28704768);            // [12][3120][128] bf16
  u16* Kb   = (u16*)(ws + 38289408);
  u16* Vt   = (u16*)(ws + 47874048);            // [1536][3120] bf16 (V^T)
  u16* Ob   = (u16*)(ws + 57458688);            // [3200][1536] bf16
  float* lin = (float*)(ws + 67289088);         // [3200][3072] fp32 (q|k)

  prep_x_kern<<<2400, 256, 0, stream>>>(x, xb);
  transpose_w_kern<<<dim3(48, 48, 4), dim3(32, 8), 0, stream>>>(
      wq, wk, wv, wo, Btq, Btq + DIMN * DIMN, Btq + 2 * DIMN * DIMN, wot);
  zero_tail_kern<<<60, 256, 0, stream>>>(Ob);

  gemm_qkv<<<dim3(25, 36), 256, 0, stream>>>(xb, Btq, bq, bk, bv, lin, Vt);
  postproc_qk<<<L_SEQ, 256, 0, stream>>>(lin, gq, gk, fc, fs, Qb, Kb);
  attn_kern<<<588, 256, 0, stream>>>(Qb, Kb, Vt, Ob);
  gemm_out<<<dim3(25, 12), 256, 0, stream>>>(Ob, wot, bo, (float*)d_out);
}

// Round 9
// 386.505 us; speedup vs baseline: 1.3781x; 1.0372x over previous
//
#include <hip/hip_runtime.h>
#include <hip/hip_bf16.h>

#define L_SEQ 3120
#define LPAD  3200
#define DIMN  1536
#define FRAME 1560
#define NHH   12
#define HDIM  128

using bh8   = __attribute__((ext_vector_type(8))) short;
using bh4   = __attribute__((ext_vector_type(4))) short;
using f32x4 = __attribute__((ext_vector_type(4))) float;
typedef unsigned short u16;
typedef unsigned int   u32;

static __device__ __forceinline__ u16 f2bf(float f) {
  __hip_bfloat16 h = __float2bfloat16(f);
  return *reinterpret_cast<u16*>(&h);
}
static __device__ __forceinline__ void gld16(const u16* g, u16* l) {
  __builtin_amdgcn_global_load_lds((const __attribute__((address_space(1))) void*)g,
                                   (__attribute__((address_space(3))) void*)l, 16, 0, 0);
}
static __device__ __forceinline__ float lanebcast(float v, int srcLane) {
  int i = __builtin_amdgcn_ds_bpermute(srcLane << 2, __float_as_int(v));
  return __int_as_float(i);
}

// ---------------- prep: x -> bf16, rows >= L zeroed ----------------
__global__ __launch_bounds__(256) void prep_x_kern(const float* __restrict__ x,
                                                   u16* __restrict__ xb) {
  int i = (blockIdx.x * 256 + threadIdx.x) * 8;   // grid covers LPAD*DIMN/8
  bh8 o;
  if (i < L_SEQ * DIMN) {
    float4 a = *(const float4*)&x[i];
    float4 b = *(const float4*)&x[i + 4];
    o[0] = (short)f2bf(a.x); o[1] = (short)f2bf(a.y);
    o[2] = (short)f2bf(a.z); o[3] = (short)f2bf(a.w);
    o[4] = (short)f2bf(b.x); o[5] = (short)f2bf(b.y);
    o[6] = (short)f2bf(b.z); o[7] = (short)f2bf(b.w);
  } else {
    o = (bh8){0, 0, 0, 0, 0, 0, 0, 0};
  }
  *(bh8*)&xb[i] = o;
}

// ---------------- weight transpose (fp32 -> bf16, W^T) ----------------
__global__ __launch_bounds__(256) void transpose_w_kern(const float* __restrict__ w0, const float* __restrict__ w1,
                                 const float* __restrict__ w2, const float* __restrict__ w3,
                                 u16* __restrict__ t0, u16* __restrict__ t1,
                                 u16* __restrict__ t2, u16* __restrict__ t3) {
  __shared__ float tile[32][33];
  const float* src; u16* dst;
  switch (blockIdx.z) {
    case 0:  src = w0; dst = t0; break;
    case 1:  src = w1; dst = t1; break;
    case 2:  src = w2; dst = t2; break;
    default: src = w3; dst = t3; break;
  }
  int k0 = blockIdx.x * 32, n0 = blockIdx.y * 32;
  int tx = threadIdx.x, ty = threadIdx.y;     // block (32,8)
  #pragma unroll
  for (int i = 0; i < 4; i++)
    tile[ty * 4 + i][tx] = src[(size_t)(k0 + ty * 4 + i) * DIMN + n0 + tx];
  __syncthreads();
  #pragma unroll
  for (int i = 0; i < 4; i++) {
    int ry = ty * 4 + i;
    dst[(size_t)(n0 + ry) * DIMN + k0 + tx] = f2bf(tile[tx][ry]);
  }
}

__global__ __launch_bounds__(256) void zero_tail_kern(u16* __restrict__ ob) {
  int i = (blockIdx.x * 256 + threadIdx.x) * 8;  // grid covers (LPAD-L_SEQ)*DIMN/8
  *(bh8*)&ob[L_SEQ * DIMN + i] = (bh8){0, 0, 0, 0, 0, 0, 0, 0};
}

// ---------------- fused QKV GEMM (m97 structure: global_load_lds, BK=64) ----------------
__global__ __launch_bounds__(256) void gemm_qkv(const u16* __restrict__ A,
                                                const u16* __restrict__ Bt,
                                                const float* __restrict__ bq,
                                                const float* __restrict__ bk,
                                                const float* __restrict__ bv,
                                                float* __restrict__ lin,
                                                u16* __restrict__ Vt) {
  __shared__ __align__(16) u16 Al[128 * 64];
  __shared__ __align__(16) u16 Bl[128 * 64];
  int t = threadIdx.x, lane = t & 63, w = t >> 6;
  int m0 = blockIdx.x * 128, n0 = blockIdx.y * 128;
  int wr = (w >> 1) * 64, wc = (w & 1) * 64;
  int r16 = lane & 15, g8 = (lane >> 4) * 8;
  int lrow = lane >> 3, lcol = (lane & 7) * 8;
  f32x4 acc[4][4];
  #pragma unroll
  for (int i = 0; i < 4; i++)
    #pragma unroll
    for (int j = 0; j < 4; j++) acc[i][j] = (f32x4){0.f, 0.f, 0.f, 0.f};

  const u16* Abase = A + (size_t)(m0 + w * 32 + lrow) * DIMN + lcol;
  const u16* Bbase = Bt + (size_t)(n0 + w * 32 + lrow) * DIMN + lcol;

  for (int kt = 0; kt < DIMN; kt += 64) {
    __syncthreads();
    #pragma unroll
    for (int j = 0; j < 4; j++) {
      gld16(Abase + (size_t)j * 8 * DIMN + kt, &Al[(w * 32 + j * 8) * 64]);
      gld16(Bbase + (size_t)j * 8 * DIMN + kt, &Bl[(w * 32 + j * 8) * 64]);
    }
    __syncthreads();
    bh8 af[2][4], bf[2][4];
    #pragma unroll
    for (int kk = 0; kk < 2; kk++) {
      #pragma unroll
      for (int i = 0; i < 4; i++)
        af[kk][i] = *(const bh8*)&Al[(wr + i * 16 + r16) * 64 + kk * 32 + g8];
      #pragma unroll
      for (int j = 0; j < 4; j++)
        bf[kk][j] = *(const bh8*)&Bl[(wc + j * 16 + r16) * 64 + kk * 32 + g8];
    }
    #pragma unroll
    for (int kk = 0; kk < 2; kk++)
      #pragma unroll
      for (int i = 0; i < 4; i++)
        #pragma unroll
        for (int j = 0; j < 4; j++)
          acc[i][j] = __builtin_amdgcn_mfma_f32_16x16x32_bf16(af[kk][i], bf[kk][j], acc[i][j], 0, 0, 0);
  }

  int cr = (lane >> 4) * 4, cc = lane & 15;
  int seg = n0 / DIMN;            // 0=q 1=k 2=v (tile never crosses a segment)
  int nb0 = n0 - seg * DIMN;
  const float* bp = (seg == 0) ? bq : (seg == 1) ? bk : bv;
  if (seg < 2) {
    #pragma unroll
    for (int j = 0; j < 4; j++) {
      int n = nb0 + wc + j * 16 + cc;
      float bvv = bp[n];
      #pragma unroll
      for (int i = 0; i < 4; i++) {
        int m = m0 + wr + i * 16 + cr;
        float* orow = lin + (size_t)m * (2 * DIMN) + seg * DIMN + n;
        #pragma unroll
        for (int r = 0; r < 4; r++) orow[(size_t)r * (2 * DIMN)] = acc[i][j][r] + bvv;
      }
    }
  } else {
    #pragma unroll
    for (int j = 0; j < 4; j++) {
      int d = nb0 + wc + j * 16 + cc;
      float bvv = bp[d];
      #pragma unroll
      for (int i = 0; i < 4; i++) {
        int m = m0 + wr + i * 16 + cr;
        if (m < L_SEQ) {
          bh4 o;
          #pragma unroll
          for (int r = 0; r < 4; r++) o[r] = (short)f2bf(acc[i][j][r] + bvv);
          *(bh4*)&Vt[(size_t)d * L_SEQ + m] = o;
        }
      }
    }
  }
}

// ---------------- out-proj GEMM ----------------
__global__ __launch_bounds__(256) void gemm_out(const u16* __restrict__ A,
                                                const u16* __restrict__ Bt,
                                                const float* __restrict__ bias,
                                                float* __restrict__ out) {
  __shared__ __align__(16) u16 Al[128 * 64];
  __shared__ __align__(16) u16 Bl[128 * 64];
  int t = threadIdx.x, lane = t & 63, w = t >> 6;
  int m0 = blockIdx.x * 128, n0 = blockIdx.y * 128;
  int wr = (w >> 1) * 64, wc = (w & 1) * 64;
  int r16 = lane & 15, g8 = (lane >> 4) * 8;
  int lrow = lane >> 3, lcol = (lane & 7) * 8;
  f32x4 acc[4][4];
  #pragma unroll
  for (int i = 0; i < 4; i++)
    #pragma unroll
    for (int j = 0; j < 4; j++) acc[i][j] = (f32x4){0.f, 0.f, 0.f, 0.f};

  const u16* Abase = A + (size_t)(m0 + w * 32 + lrow) * DIMN + lcol;
  const u16* Bbase = Bt + (size_t)(n0 + w * 32 + lrow) * DIMN + lcol;

  for (int kt = 0; kt < DIMN; kt += 64) {
    __syncthreads();
    #pragma unroll
    for (int j = 0; j < 4; j++) {
      gld16(Abase + (size_t)j * 8 * DIMN + kt, &Al[(w * 32 + j * 8) * 64]);
      gld16(Bbase + (size_t)j * 8 * DIMN + kt, &Bl[(w * 32 + j * 8) * 64]);
    }
    __syncthreads();
    bh8 af[2][4], bf[2][4];
    #pragma unroll
    for (int kk = 0; kk < 2; kk++) {
      #pragma unroll
      for (int i = 0; i < 4; i++)
        af[kk][i] = *(const bh8*)&Al[(wr + i * 16 + r16) * 64 + kk * 32 + g8];
      #pragma unroll
      for (int j = 0; j < 4; j++)
        bf[kk][j] = *(const bh8*)&Bl[(wc + j * 16 + r16) * 64 + kk * 32 + g8];
    }
    #pragma unroll
    for (int kk = 0; kk < 2; kk++)
      #pragma unroll
      for (int i = 0; i < 4; i++)
        #pragma unroll
        for (int j = 0; j < 4; j++)
          acc[i][j] = __builtin_amdgcn_mfma_f32_16x16x32_bf16(af[kk][i], bf[kk][j], acc[i][j], 0, 0, 0);
  }

  int cr = (lane >> 4) * 4, cc = lane & 15;
  #pragma unroll
  for (int j = 0; j < 4; j++) {
    int n = n0 + wc + j * 16 + cc;
    float bvv = bias[n];
    #pragma unroll
    for (int i = 0; i < 4; i++) {
      int m = m0 + wr + i * 16 + cr;
      if (m < L_SEQ) {
        #pragma unroll
        for (int r = 0; r < 4; r++) out[(size_t)(m + r) * DIMN + n] = acc[i][j][r] + bvv;
      }
    }
  }
}

// ---------------- fused RMSNorm + RoPE for q,k ----------------
__global__ __launch_bounds__(256) void postproc_qk(const float* __restrict__ lin,
                                                   const float* __restrict__ gq,
                                                   const float* __restrict__ gk,
                                                   const float* __restrict__ fc,
                                                   const float* __restrict__ fs,
                                                   u16* __restrict__ Qb, u16* __restrict__ Kb) {
  int l = blockIdx.x, t = threadIdx.x;
  int lane = t & 63, w = t >> 6;
  const float2* qr = (const float2*)(lin + (size_t)l * (2 * DIMN));
  const float2* kr = qr + DIMN / 2;
  float2 qv[3], kv[3];
  float ssq = 0.f, ssk = 0.f;
  #pragma unroll
  for (int j = 0; j < 3; j++) {
    qv[j] = qr[t + j * 256];
    kv[j] = kr[t + j * 256];
    ssq += qv[j].x * qv[j].x + qv[j].y * qv[j].y;
    ssk += kv[j].x * kv[j].x + kv[j].y * kv[j].y;
  }
  __shared__ float red[8];
  #pragma unroll
  for (int off = 32; off; off >>= 1) {
    ssq += __shfl_xor(ssq, off);
    ssk += __shfl_xor(ssk, off);
  }
  if (lane == 0) { red[w] = ssq; red[4 + w] = ssk; }
  __syncthreads();
  float rrq = rsqrtf((red[0] + red[1] + red[2] + red[3]) * (1.0f / DIMN) + 1e-6f);
  float rrk = rsqrtf((red[4] + red[5] + red[6] + red[7]) * (1.0f / DIMN) + 1e-6f);
  u32* qo = (u32*)Qb;
  u32* ko = (u32*)Kb;
  #pragma unroll
  for (int j = 0; j < 3; j++) {
    int p = t + j * 256;              // pair index 0..767
    int head = p >> 6, c = p & 63;
    float co = fc[l * 64 + c], si = fs[l * 64 + c];
    float2 g2, o;
    size_t idx = ((size_t)head * L_SEQ + l) * 64 + c;
    g2 = ((const float2*)gq)[p];
    o.x = qv[j].x * rrq * g2.x; o.y = qv[j].y * rrq * g2.y;
    qo[idx] = (u32)f2bf(o.x * co - o.y * si) | ((u32)f2bf(o.x * si + o.y * co) << 16);
    g2 = ((const float2*)gk)[p];
    o.x = kv[j].x * rrk * g2.x; o.y = kv[j].y * rrk * g2.y;
    ko[idx] = (u32)f2bf(o.x * co - o.y * si) | ((u32)f2bf(o.x * si + o.y * co) << 16);
  }
}

// ---------------- flash attention: R4 base + swapped QK^T (S=[key][q]) ----------------
// Each lane owns ONE query row (q = qr0 + lane&15); 4 lanes/row hold disjoint key slices.
// Softmax is per-lane scalar; row reduce = 2 shfl_xor (only on rescale + final).
// P written transposed-in-place into [q][key] LDS; P-read/PV byte-identical to R4.
__global__ __launch_bounds__(256) void attn_kern(const u16* __restrict__ Q,
                                                 const u16* __restrict__ K,
                                                 const u16* __restrict__ Vt,
                                                 u16* __restrict__ Ob) {
  __shared__ __align__(16) u16 KlB[2][64 * 128];   // 32 KB
  __shared__ __align__(16) u16 VlB[2][128 * 64];   // 32 KB
  __shared__ __align__(16) u16 Pl[4][16 * 72];     // 9 KB
  int t = threadIdx.x, lane = t & 63, w = t >> 6;
  int h = blockIdx.y;
  int bx = 48 - blockIdx.x;                        // heavy (full-causal) blocks first
  int qb = bx * 64, qr0 = qb + w * 16;
  int r16 = lane & 15, grp = lane >> 4, g8 = grp * 8;
  int cr = grp * 4, cc = lane & 15;
  const float sl = 0.08838834764831845f * 1.4426950408889634f;  // SCALE * log2(e)

  int qld = qr0 + r16; if (qld > L_SEQ - 1) qld = L_SEQ - 1;
  const u16* qrow = Q + ((size_t)h * L_SEQ + qld) * HDIM;
  bh8 qf[4];
  #pragma unroll
  for (int kk = 0; kk < 4; kk++) qf[kk] = *(const bh8*)&qrow[kk * 32 + g8];

  const u16* Kbase = K + (size_t)h * L_SEQ * HDIM;
  const u16* Vbase = Vt + (size_t)h * HDIM * L_SEQ;

  // per-lane row state (row q = qr0 + r16)
  int klim = (qr0 + r16 < FRAME) ? FRAME : L_SEQ;
  float m_run = -3.0e38f, l_part = 0.f;
  f32x4 accO[8];
  #pragma unroll
  for (int i = 0; i < 8; i++) accO[i] = (f32x4){0.f, 0.f, 0.f, 0.f};

  int klim_min = (qr0 < FRAME) ? FRAME : L_SEQ;
  int klimB = (qb + 63 < FRAME) ? FRAME : L_SEQ;
  int nkt = (klimB + 63) >> 6;
  int srcr[4];                                     // bpermute lanes for accO rows cr+r
  #pragma unroll
  for (int r = 0; r < 4; r++) srcr[r] = ((lane & 48) | (cr + r)) << 2;

  // 8 gld16 per wave per tile (K: 16 rows of 4x16B; V: 32 rows of 8x16B)
  auto stage = [&](int buf, int it) {
    int kt = it << 6;
    #pragma unroll
    for (int j = 0; j < 4; j++) {
      int rr = w * 16 + j * 4 + (lane >> 4);
      int grow = kt + rr; grow = (grow > L_SEQ - 1) ? L_SEQ - 1 : grow;
      int gc = ((lane & 15) ^ (rr & 7)) * 8;
      gld16(Kbase + (size_t)grow * HDIM + gc, &KlB[buf][(w * 16 + j * 4) * 128]);
    }
    #pragma unroll
    for (int j = 0; j < 4; j++) {
      int vr = w * 32 + j * 8 + (lane >> 3);
      int gc = kt + ((lane & 7) ^ (vr & 7)) * 8;
      gc = (gc > L_SEQ - 8) ? L_SEQ - 8 : gc;
      gld16(Vbase + (size_t)vr * L_SEQ + gc, &VlB[buf][(w * 32 + j * 8) * 64]);
    }
  };

  stage(0, 0);
  for (int it = 0; it < nkt; ++it) {
    int buf = it & 1, kt = it << 6;
    if (it + 1 < nkt) {
      stage(buf ^ 1, it + 1);
      asm volatile("s_waitcnt vmcnt(8)" ::: "memory");   // tile-it loads retired
    } else {
      asm volatile("s_waitcnt vmcnt(0)" ::: "memory");
    }
    __builtin_amdgcn_s_barrier();
    __builtin_amdgcn_sched_barrier(0);

    // QK^T swapped: S[key][q] = mfma(A=K, B=Q). Same frag reads as R4, args swapped.
    f32x4 s[4];
    #pragma unroll
    for (int sb = 0; sb < 4; sb++) s[sb] = (f32x4){0.f, 0.f, 0.f, 0.f};
    #pragma unroll
    for (int kk = 0; kk < 4; kk++)
      #pragma unroll
      for (int sb = 0; sb < 4; sb++) {
        int rr = sb * 16 + r16;
        bh8 kf = *(const bh8*)&KlB[buf][rr * 128 + (((kk * 4 + grp) ^ (rr & 7)) * 8)];
        s[sb] = __builtin_amdgcn_mfma_f32_16x16x32_bf16(kf, qf[kk], s[sb], 0, 0, 0);
      }

    // scale + boundary-only mask: s[sb][r] = S[key = kt+sb*16+cr+r][q = qr0+r16]
    float v[4][4];
    if (kt + 64 > klim_min) {
      #pragma unroll
      for (int sb = 0; sb < 4; sb++) {
        #pragma unroll
        for (int r = 0; r < 4; r++) {
          int key = kt + sb * 16 + cr + r;
          v[sb][r] = (key < klim) ? s[sb][r] * sl : -3.0e38f;
        }
      }
    } else {
      #pragma unroll
      for (int sb = 0; sb < 4; sb++)
        #pragma unroll
        for (int r = 0; r < 4; r++) v[sb][r] = s[sb][r] * sl;
    }

    // per-lane partial max over this lane's 16 keys of its row
    float mloc = v[0][0];
    #pragma unroll
    for (int sb = 0; sb < 4; sb++)
      #pragma unroll
      for (int r = 0; r < 4; r++) mloc = fmaxf(mloc, v[sb][r]);

    if (__any((int)(mloc > m_run + 8.f))) {
      float mx = mloc;
      mx = fmaxf(mx, __shfl_xor(mx, 16));
      mx = fmaxf(mx, __shfl_xor(mx, 32));          // row max over the 4 lane-copies
      float mnew = fmaxf(m_run, mx);
      float fac = exp2f(m_run - mnew);
      m_run = mnew;
      l_part *= fac;
      float facr[4];                               // fac for accO rows cr+r
      #pragma unroll
      for (int r = 0; r < 4; r++)
        facr[r] = __int_as_float(__builtin_amdgcn_ds_bpermute(srcr[r], __float_as_int(fac)));
      #pragma unroll
      for (int nb = 0; nb < 8; nb++)
        #pragma unroll
        for (int r = 0; r < 4; r++) accO[nb][r] *= facr[r];
    }

    // P = exp2(v - m_run); write transposed-in-place: row q=r16, col key_local
    #pragma unroll
    for (int sb = 0; sb < 4; sb++)
      #pragma unroll
      for (int r = 0; r < 4; r++) {
        float p = exp2f(v[sb][r] - m_run);
        l_part += p;
        Pl[w][r16 * 72 + sb * 16 + cr + r] = f2bf(p);
      }

    bh8 pf0 = *(const bh8*)&Pl[w][r16 * 72 + g8];
    bh8 pf1 = *(const bh8*)&Pl[w][r16 * 72 + 32 + g8];
    #pragma unroll
    for (int nb = 0; nb < 8; nb++) {
      int vrow = nb * 16 + r16;
      bh8 vf0 = *(const bh8*)&VlB[buf][vrow * 64 + ((grp ^ (vrow & 7)) * 8)];
      bh8 vf1 = *(const bh8*)&VlB[buf][vrow * 64 + (((4 + grp) ^ (vrow & 7)) * 8)];
      accO[nb] = __builtin_amdgcn_mfma_f32_16x16x32_bf16(pf0, vf0, accO[nb], 0, 0, 0);
      accO[nb] = __builtin_amdgcn_mfma_f32_16x16x32_bf16(pf1, vf1, accO[nb], 0, 0, 0);
    }
    __builtin_amdgcn_s_barrier();   // all waves done reading buf before it's re-staged
  }

  // row sum: combine 4 per-lane partials, then redistribute 1/l to accO rows
  l_part += __shfl_xor(l_part, 16);
  l_part += __shfl_xor(l_part, 32);
  float linv = 1.0f / l_part;
  float linvr[4];
  #pragma unroll
  for (int r = 0; r < 4; r++)
    linvr[r] = __int_as_float(__builtin_amdgcn_ds_bpermute(srcr[r], __float_as_int(linv)));
  #pragma unroll
  for (int nb = 0; nb < 8; nb++)
    #pragma unroll
    for (int r = 0; r < 4; r++) {
      int qi = qr0 + cr + r;
      if (qi < L_SEQ)
        Ob[(size_t)qi * DIMN + h * HDIM + nb * 16 + cc] = f2bf(accO[nb][r] * linvr[r]);
    }
}

// ---------------- host launch ----------------
extern "C" void kernel_launch(void* const* d_in, const int* in_sizes, int n_in,
                              void* d_out, int out_size, void* d_ws, size_t ws_size,
                              hipStream_t stream) {
  const float* x  = (const float*)d_in[0];
  const float* wq = (const float*)d_in[1];
  const float* wk = (const float*)d_in[2];
  const float* wv = (const float*)d_in[3];
  const float* wo = (const float*)d_in[4];
  const float* bq = (const float*)d_in[5];
  const float* bk = (const float*)d_in[6];
  const float* bv = (const float*)d_in[7];
  const float* bo = (const float*)d_in[8];
  const float* gq = (const float*)d_in[9];
  const float* gk = (const float*)d_in[10];
  const float* fc = (const float*)d_in[11];
  const float* fs = (const float*)d_in[12];

  char* ws = (char*)d_ws;
  u16* xb   = (u16*)(ws);                       // [3200][1536] bf16
  u16* Btq  = (u16*)(ws + 9830400);             // [4608][1536] bf16 (wq|wk|wv)^T
  u16* wot  = (u16*)(ws + 23986176);            // [1536][1536] bf16 wo^T
  u16* Qb   = (u16*)(ws + 28704768);            // [12][3120][128] bf16
  u16* Kb   = (u16*)(ws + 38289408);
  u16* Vt   = (u16*)(ws + 47874048);            // [1536][3120] bf16 (V^T)
  u16* Ob   = (u16*)(ws + 57458688);            // [3200][1536] bf16
  float* lin = (float*)(ws + 67289088);         // [3200][3072] fp32 (q|k)

  prep_x_kern<<<2400, 256, 0, stream>>>(x, xb);
  transpose_w_kern<<<dim3(48, 48, 4), dim3(32, 8), 0, stream>>>(
      wq, wk, wv, wo, Btq, Btq + DIMN * DIMN, Btq + 2 * DIMN * DIMN, wot);
  zero_tail_kern<<<60, 256, 0, stream>>>(Ob);

  gemm_qkv<<<dim3(25, 36), 256, 0, stream>>>(xb, Btq, bq, bk, bv, lin, Vt);
  postproc_qk<<<L_SEQ, 256, 0, stream>>>(lin, gq, gk, fc, fs, Qb, Kb);
  attn_kern<<<dim3(49, 12), 256, 0, stream>>>(Qb, Kb, Vt, Ob);
  gemm_out<<<dim3(25, 12), 256, 0, stream>>>(Ob, wot, bo, (float*)d_out);
}